// Round 2
// baseline (105.088 us; speedup 1.0000x reference)
//
#include <hip/hip_runtime.h>

// CosineAttention collapses to a linear map:
//   out[q] = (q_hat @ M + u) / (q_hat . s + n)
// with per-(b,h) moments over masked keys:
//   M[j][d] = sum_k m_k khat[k][j] V[k][d]   (64x64)
//   s[j]    = sum_k m_k khat[k][j]   u[d] = sum_k m_k V[k][d]   n = sum_k m_k
//
// R10 (occupancy + dep-chain cut; kernels are latency-bound, not BW-bound):
//  k1: 512 threads/block (8 waves) -> 16 waves/CU (was 8). Each wave stages
//      16 keys (4 iters); waves 0-3 run the K=32 MFMA on one 32-key region.
//      bf16 packing via v_cvt_pk_bf16_f32 (1 op vs ~7 integer ops/pair).
//  k2: unchanged.
//  k3: 1024 blocks x 64 rows (cc loop dropped) -> 16 waves/CU; cvt_pk pack.

#define S 4096
#define D 64
#define BH 16
#define FSTRIDE 4352
#define NE 4225          // 4096 (M) + 64 (s) + 64 (u) + 1 (n)
#define NCHM 32          // moments: 128 keys per block
#define KSTR 36          // staging dim-row stride in shorts (32 keys + 4 pad)
#define QSTR 72          // k3 Qst dim stride in shorts
#define PSTR 8832        // partial stride BYTES: 4096 u16 (M) + 129 f32, padded
#define FTSTR 4224       // finTh per-bh stride in shorts: 4096 M^T + 64 s + pad

typedef __attribute__((ext_vector_type(8))) short short8;
typedef __attribute__((ext_vector_type(4))) short short4v;
typedef __attribute__((ext_vector_type(4))) float f32x4;

__device__ __forceinline__ float bperm(float v, int srclane) {
    return __int_as_float(
        __builtin_amdgcn_ds_bpermute(srclane << 2, __float_as_int(v)));
}
__device__ __forceinline__ unsigned bf16h(float x) {
    unsigned u = __float_as_uint(x);
    u += 0x7FFF + ((u >> 16) & 1);          // round-nearest-even
    return u >> 16;
}
__device__ __forceinline__ float bf16f(unsigned short h) {
    return __uint_as_float(((unsigned)h) << 16);
}
// packed f32x2 -> bf16x2 (RNE), single VALU op; lo = a, hi = b
__device__ __forceinline__ unsigned cvt_pk_bf16(float a, float b) {
    unsigned r;
    asm("v_cvt_pk_bf16_f32 %0, %1, %2" : "=v"(r) : "v"(a), "v"(b));
    return r;
}

// ------ kernel 1: partial moments, single K/V pass, 8 waves/block ---------
__global__ __launch_bounds__(512, 4) void k_moments(
    const float* __restrict__ K, const float* __restrict__ V,
    const int* __restrict__ mask, char* __restrict__ part)
{
    __shared__ unsigned short stag[8 * 64 * KSTR];   // 36864 B: 4 K + 4 V regions
    __shared__ float sured[8 * 132];
    float* red0 = (float*)stag;                      // merge aliases staging
    float* red1 = red0 + 4096;

    const int tid  = threadIdx.x;
    const int lane = tid & 63;
    const int wave = tid >> 6;           // 0..7
    const int quad = lane >> 4;
    const int l15  = lane & 15;
    const int pair = wave >> 1;          // 32-key region 0..3
    const int half = wave & 1;           // which 16 keys of the region

    const int bh    = blockIdx.x >> 5;
    const int chunk = blockIdx.x & 31;
    const int row0  = chunk * 128 + pair * 32 + half * 16;  // wave's 16 keys

    const float* Kh = K + (size_t)bh * S * D;
    const float* Vh = V + (size_t)bh * S * D;
    const int*   mb = mask + (bh >> 3) * S;          // mask [B,1,1,S], H=8

    // staging: float4 loads; lane covers dims 4*l15..+3, key 4*quad+i.
    // Key row lives across the 16 lanes of the quad group -> norm via
    // 4-hop shfl_xor reduce.
    unsigned short* Kst = stag + pair * (64 * KSTR);
    unsigned short* Vst = stag + 4 * (64 * KSTR) + pair * (64 * KSTR);
    unsigned* KstW = (unsigned*)Kst;
    unsigned* VstW = (unsigned*)Vst;

    float4 s4 = {0.f, 0.f, 0.f, 0.f}, u4 = {0.f, 0.f, 0.f, 0.f};
    float nwp = 0.f;
    float kprev[4], vprev[4];
    #pragma unroll
    for (int i = 0; i < 4; ++i) {
        const int row = row0 + 4 * quad + i;
        float4 kf = *(const float4*)(Kh + (size_t)row * D + 4 * l15);
        float4 vf = *(const float4*)(Vh + (size_t)row * D + 4 * l15);
        float ssp = kf.x * kf.x;
        ssp = fmaf(kf.y, kf.y, ssp);
        ssp = fmaf(kf.z, kf.z, ssp);
        ssp = fmaf(kf.w, kf.w, ssp);
        ssp += __shfl_xor(ssp, 1, 64);
        ssp += __shfl_xor(ssp, 2, 64);
        ssp += __shfl_xor(ssp, 4, 64);
        ssp += __shfl_xor(ssp, 8, 64);               // full-row sum-of-squares
        const float mj = (float)mb[row];
        nwp += mj;
        // 1/max(sqrt(ss),1e-12) == rsq(max(ss,1e-24)); masked -> 0
        const float aj = mj * __builtin_amdgcn_rsqf(fmaxf(ssp, 1e-24f));
        float k0 = kf.x * aj, k1 = kf.y * aj, k2 = kf.z * aj, k3 = kf.w * aj;
        float v0 = vf.x * mj, v1 = vf.y * mj, v2 = vf.z * mj, v3 = vf.w * mj;
        s4.x += k0; s4.y += k1; s4.z += k2; s4.w += k3;
        u4.x += v0; u4.y += v1; u4.z += v2; u4.w += v3;
        if (i & 1) {
            // key within region: kk = 16*half + 4*quad + i; word = kk>>1
            const int base = 8 * half + 2 * quad + (i >> 1);
            KstW[(4 * l15 + 0) * 18 + base] = cvt_pk_bf16(kprev[0], k0);
            KstW[(4 * l15 + 1) * 18 + base] = cvt_pk_bf16(kprev[1], k1);
            KstW[(4 * l15 + 2) * 18 + base] = cvt_pk_bf16(kprev[2], k2);
            KstW[(4 * l15 + 3) * 18 + base] = cvt_pk_bf16(kprev[3], k3);
            VstW[(4 * l15 + 0) * 18 + base] = cvt_pk_bf16(vprev[0], v0);
            VstW[(4 * l15 + 1) * 18 + base] = cvt_pk_bf16(vprev[1], v1);
            VstW[(4 * l15 + 2) * 18 + base] = cvt_pk_bf16(vprev[2], v2);
            VstW[(4 * l15 + 3) * 18 + base] = cvt_pk_bf16(vprev[3], v3);
        } else {
            kprev[0] = k0; kprev[1] = k1; kprev[2] = k2; kprev[3] = k3;
            vprev[0] = v0; vprev[1] = v1; vprev[2] = v2; vprev[3] = v3;
        }
    }
    // nwp identical across the 16 lanes of a quad group; summing the 4
    // quads (xor 16, 32) counts each of the wave's 16 keys exactly once.
    float nw = nwp;
    nw += __shfl_xor(nw, 16, 64);
    nw += __shfl_xor(nw, 32, 64);

    s4.x += __shfl_xor(s4.x, 16, 64); s4.x += __shfl_xor(s4.x, 32, 64);
    s4.y += __shfl_xor(s4.y, 16, 64); s4.y += __shfl_xor(s4.y, 32, 64);
    s4.z += __shfl_xor(s4.z, 16, 64); s4.z += __shfl_xor(s4.z, 32, 64);
    s4.w += __shfl_xor(s4.w, 16, 64); s4.w += __shfl_xor(s4.w, 32, 64);
    u4.x += __shfl_xor(u4.x, 16, 64); u4.x += __shfl_xor(u4.x, 32, 64);
    u4.y += __shfl_xor(u4.y, 16, 64); u4.y += __shfl_xor(u4.y, 32, 64);
    u4.z += __shfl_xor(u4.z, 16, 64); u4.z += __shfl_xor(u4.z, 32, 64);
    u4.w += __shfl_xor(u4.w, 16, 64); u4.w += __shfl_xor(u4.w, 32, 64);
    if (quad == 0) {
        sured[wave * 132 + 4 * l15 + 0]      = s4.x;
        sured[wave * 132 + 4 * l15 + 1]      = s4.y;
        sured[wave * 132 + 4 * l15 + 2]      = s4.z;
        sured[wave * 132 + 4 * l15 + 3]      = s4.w;
        sured[wave * 132 + 64 + 4 * l15 + 0] = u4.x;
        sured[wave * 132 + 64 + 4 * l15 + 1] = u4.y;
        sured[wave * 132 + 64 + 4 * l15 + 2] = u4.z;
        sured[wave * 132 + 64 + 4 * l15 + 3] = u4.w;
    }
    if (lane == 0) sured[wave * 132 + 128] = nw;
    __syncthreads();

    // MFMA over K=32 keys: wave w<4 owns region w
    f32x4 acc[4][4];
    if (wave < 4) {
        const unsigned short* Kr = stag + wave * (64 * KSTR);
        const unsigned short* Vr = stag + 4 * (64 * KSTR) + wave * (64 * KSTR);
        short8 af[4], bfr[4];
        #pragma unroll
        for (int t = 0; t < 4; ++t) {
            const unsigned short* ab = Kr + (t * 16 + l15) * KSTR + quad * 8;
            short4v a0 = *(const short4v*)ab;
            short4v a1 = *(const short4v*)(ab + 4);
            af[t] = __builtin_shufflevector(a0, a1, 0, 1, 2, 3, 4, 5, 6, 7);
            const unsigned short* bb = Vr + (t * 16 + l15) * KSTR + quad * 8;
            short4v b0 = *(const short4v*)bb;
            short4v b1 = *(const short4v*)(bb + 4);
            bfr[t] = __builtin_shufflevector(b0, b1, 0, 1, 2, 3, 4, 5, 6, 7);
        }
        #pragma unroll
        for (int tm = 0; tm < 4; ++tm)
            #pragma unroll
            for (int tn = 0; tn < 4; ++tn)
                acc[tm][tn] = (f32x4){0.f, 0.f, 0.f, 0.f};
        #pragma unroll
        for (int tn = 0; tn < 4; ++tn)
            #pragma unroll
            for (int tm = 0; tm < 4; ++tm)
                acc[tm][tn] = __builtin_amdgcn_mfma_f32_16x16x32_bf16(
                    af[tm], bfr[tn], acc[tm][tn], 0, 0, 0);
    }
    __syncthreads();

    // pairwise merge aliasing staging: waves 0/1 write, 2/3 add
    if (wave < 2) {
        float* rd = wave ? red1 : red0;
        #pragma unroll
        for (int tm = 0; tm < 4; ++tm)
            #pragma unroll
            for (int tn = 0; tn < 4; ++tn)
                #pragma unroll
                for (int rr = 0; rr < 4; ++rr)
                    rd[(tm * 16 + quad * 4 + rr) * 64 + tn * 16 + l15]
                        = acc[tm][tn][rr];
    }
    __syncthreads();
    if (wave == 2 || wave == 3) {
        float* rd = (wave == 3) ? red1 : red0;
        #pragma unroll
        for (int tm = 0; tm < 4; ++tm)
            #pragma unroll
            for (int tn = 0; tn < 4; ++tn)
                #pragma unroll
                for (int rr = 0; rr < 4; ++rr)
                    rd[(tm * 16 + quad * 4 + rr) * 64 + tn * 16 + l15]
                        += acc[tm][tn][rr];
    }
    __syncthreads();

    char* pb = part + ((size_t)bh * NCHM + chunk) * PSTR;
    unsigned short* pm = (unsigned short*)pb;
    float* psu = (float*)(pb + 8192);
    for (int i = tid; i < NE; i += 512) {
        if (i < 4096)
            pm[i] = (unsigned short)bf16h(red0[i] + red1[i]);
        else {
            int e = i - 4096;
            float v = 0.f;
            #pragma unroll
            for (int w = 0; w < 8; ++w) v += sured[w * 132 + e];
            psu[e] = v;
        }
    }
}

// ------ kernel 2: reduce partials -> fin (fp32) + finTh (bf16 M^T, s) ----
__global__ __launch_bounds__(256) void k_reduce(
    const char* __restrict__ part, float* __restrict__ fin,
    unsigned short* __restrict__ finTh)
{
    const int bh = blockIdx.x;
    const int e  = blockIdx.y * 256 + threadIdx.x;
    if (e >= NE) return;
    const char* pb = part + (size_t)bh * NCHM * PSTR;
    if (e < 4096) {
        float a0 = 0.f, a1 = 0.f, a2 = 0.f, a3 = 0.f;
        #pragma unroll
        for (int c = 0; c < NCHM; c += 4) {
            a0 += bf16f(*(const unsigned short*)(pb + (size_t)(c + 0) * PSTR + 2 * e));
            a1 += bf16f(*(const unsigned short*)(pb + (size_t)(c + 1) * PSTR + 2 * e));
            a2 += bf16f(*(const unsigned short*)(pb + (size_t)(c + 2) * PSTR + 2 * e));
            a3 += bf16f(*(const unsigned short*)(pb + (size_t)(c + 3) * PSTR + 2 * e));
        }
        float v = (a0 + a1) + (a2 + a3);
        finTh[(size_t)bh * FTSTR + (e & 63) * 64 + (e >> 6)] = (unsigned short)bf16h(v);
    } else {
        const int eo = e - 4096;
        float a0 = 0.f, a1 = 0.f, a2 = 0.f, a3 = 0.f;
        #pragma unroll
        for (int c = 0; c < NCHM; c += 4) {
            a0 += *(const float*)(pb + (size_t)(c + 0) * PSTR + 8192 + 4 * eo);
            a1 += *(const float*)(pb + (size_t)(c + 1) * PSTR + 8192 + 4 * eo);
            a2 += *(const float*)(pb + (size_t)(c + 2) * PSTR + 8192 + 4 * eo);
            a3 += *(const float*)(pb + (size_t)(c + 3) * PSTR + 8192 + 4 * eo);
        }
        float v = (a0 + a1) + (a2 + a3);
        fin[(size_t)bh * FSTRIDE + e] = v;
        if (eo < 64)    // bf16 s for k3's denominator MFMA column
            finTh[(size_t)bh * FTSTR + 4096 + eo] = (unsigned short)bf16h(v);
    }
}

// ------ kernel 3: out = (qhat M + u) / (qhat.s + n), den via MFMA --------
// grid 1024 blocks x 256; 64 rows/block; B-frags loaded once.
// Q-norm computed inline: row lives across the 16 lanes of the quad group.
__global__ __launch_bounds__(256) void k_out(
    const float* __restrict__ Q, const float* __restrict__ fin,
    const unsigned short* __restrict__ finTh, float* __restrict__ out)
{
    __shared__ unsigned short Qst[4 * 16 * QSTR];

    const int tid  = threadIdx.x;
    const int lane = tid & 63;
    const int wave = tid >> 6;
    const int quad = lane >> 4;
    const int l15  = lane & 15;

    const int bh  = blockIdx.x >> 6;
    const int c64 = blockIdx.x & 63;

    const float* fb = fin + (size_t)bh * FSTRIDE;
    const unsigned short* fT = finTh + (size_t)bh * FTSTR;
    const float* Qh = Q + (size_t)bh * S * D;
    float*       Oh = out + (size_t)bh * S * D;

    const float nval = fb[4224];
    float uo[4];
    #pragma unroll
    for (int tn = 0; tn < 4; ++tn) uo[tn] = fb[4160 + tn * 16 + l15];

    short8 bf0[4], bf1[4];              // M^T B-frags, loaded once
    #pragma unroll
    for (int tn = 0; tn < 4; ++tn) {
        bf0[tn] = *(const short8*)(fT + (tn * 16 + l15) * 64 + quad * 8);
        bf1[tn] = *(const short8*)(fT + (tn * 16 + l15) * 64 + 32 + quad * 8);
    }
    // s-column B-frags: col 0 = s, other cols 0
    short8 sz = {0, 0, 0, 0, 0, 0, 0, 0};
    short8 sv0 = *(const short8*)(fT + 4096 + quad * 8);
    short8 sv1 = *(const short8*)(fT + 4096 + 32 + quad * 8);
    short8 bs0 = (l15 == 0) ? sv0 : sz;
    short8 bs1 = (l15 == 0) ? sv1 : sz;

    unsigned short* Qw = Qst + wave * 16 * QSTR;
    const int row0w = c64 * 64 + wave * 16;

    // stage qhat bf16 [row][dim]: norm via shfl_xor reduce, then cvt_pk pack
    #pragma unroll
    for (int i = 0; i < 4; ++i) {
        const int r = 4 * quad + i;
        float4 qv = *(const float4*)(Qh + (size_t)(row0w + r) * D + 4 * l15);
        float ssp = qv.x * qv.x;
        ssp = fmaf(qv.y, qv.y, ssp);
        ssp = fmaf(qv.z, qv.z, ssp);
        ssp = fmaf(qv.w, qv.w, ssp);
        ssp += __shfl_xor(ssp, 1, 64);
        ssp += __shfl_xor(ssp, 2, 64);
        ssp += __shfl_xor(ssp, 4, 64);
        ssp += __shfl_xor(ssp, 8, 64);
        const float iq = __builtin_amdgcn_rsqf(fmaxf(ssp, 1e-24f));
        uint2 w;
        w.x = cvt_pk_bf16(qv.x * iq, qv.y * iq);
        w.y = cvt_pk_bf16(qv.z * iq, qv.w * iq);
        *(uint2*)(Qw + r * QSTR + 4 * l15) = w;
    }
    asm volatile("" ::: "memory");

    short8 af0 = *(const short8*)(Qw + l15 * QSTR + quad * 8);
    short8 af1 = *(const short8*)(Qw + l15 * QSTR + 32 + quad * 8);

    f32x4 acc[4], acc5;
    #pragma unroll
    for (int tn = 0; tn < 4; ++tn) acc[tn] = (f32x4){0.f, 0.f, 0.f, 0.f};
    acc5 = (f32x4){0.f, 0.f, 0.f, 0.f};
    #pragma unroll
    for (int tn = 0; tn < 4; ++tn) {
        acc[tn] = __builtin_amdgcn_mfma_f32_16x16x32_bf16(af0, bf0[tn], acc[tn], 0, 0, 0);
        acc[tn] = __builtin_amdgcn_mfma_f32_16x16x32_bf16(af1, bf1[tn], acc[tn], 0, 0, 0);
    }
    acc5 = __builtin_amdgcn_mfma_f32_16x16x32_bf16(af0, bs0, acc5, 0, 0, 0);
    acc5 = __builtin_amdgcn_mfma_f32_16x16x32_bf16(af1, bs1, acc5, 0, 0, 0);

    // epilogue: C/D row = quad*4+rr, col = l15; den from acc5 col 0
    #pragma unroll
    for (int rr = 0; rr < 4; ++rr) {
        float den = bperm(acc5[rr], 16 * quad) + nval;
        float rd = 1.f / den;
        const size_t row = row0w + quad * 4 + rr;
        #pragma unroll
        for (int tn = 0; tn < 4; ++tn)
            Oh[row * D + tn * 16 + l15] = (acc[tn][rr] + uo[tn]) * rd;
    }
}

extern "C" void kernel_launch(void* const* d_in, const int* in_sizes, int n_in,
                              void* d_out, int out_size, void* d_ws, size_t ws_size,
                              hipStream_t stream) {
    const float* Q    = (const float*)d_in[0];
    const float* K    = (const float*)d_in[1];
    const float* V    = (const float*)d_in[2];
    const int*   mask = (const int*)d_in[3];
    float* out = (float*)d_out;
    char*  ws  = (char*)d_ws;

    float*          fin   = (float*)ws;                          // BH*FSTRIDE f32
    unsigned short* finTh = (unsigned short*)(ws + (size_t)BH * FSTRIDE * 4);
    char*           part  = (char*)finTh + (size_t)BH * FTSTR * 2; // BH*NCHM*PSTR

    k_moments<<<dim3(512), 512, 0, stream>>>(K, V, mask, part);
    k_reduce <<<dim3(BH, (NE + 255) / 256), 256, 0, stream>>>(part, fin, finTh);
    k_out    <<<dim3(1024), 256, 0, stream>>>(Q, fin, finTh, out);
}